// Round 4
// baseline (61.550 us; speedup 1.0000x reference)
//
#include <hip/hip_runtime.h>

// B=32768, D=1024, K=8, NS=10. One WAVE per row; zero LDS; zero barriers.
// Lane i owns x[16i..16i+15]. Halo via __shfl_up. Reflection at lane 0 via
// register-select overrides (reflected index is compile-time).
#define D_LEN 1024
#define NS    10

typedef float floatx4 __attribute__((ext_vector_type(4)));

__global__ __launch_bounds__(256) void wavecore_kernel(
    const float* __restrict__ x,
    const float* __restrict__ dec_lo, const float* __restrict__ dec_hi,
    const float* __restrict__ rec_lo, const float* __restrict__ rec_hi,
    const float* __restrict__ sp_c,   const int* __restrict__ sp_i,
    float* __restrict__ out)
{
    const int lane = threadIdx.x & 63;
    const int row  = blockIdx.x * 4 + (threadIdx.x >> 6);
    const size_t base = (size_t)row * D_LEN + (size_t)lane * 16;

    // Filters (uniform addresses -> scalar loads/SGPRs)
    float f_dlo[8], f_dhi[8], f_rlo[8], f_rhi[8];
#pragma unroll
    for (int k = 0; k < 8; ++k) {
        f_dlo[k] = dec_lo[k]; f_dhi[k] = dec_hi[k];
        f_rlo[k] = rec_lo[k]; f_rhi[k] = rec_hi[k];
    }

    // ---- Load own 16 x values (4x dwordx4) ----
    const floatx4* xv4 = (const floatx4*)(x + base);
    const floatx4 x0 = xv4[0], x1 = xv4[1], x2 = xv4[2], x3 = xv4[3];
    float xr[16];
    xr[0]=x0.x;  xr[1]=x0.y;  xr[2]=x0.z;  xr[3]=x0.w;
    xr[4]=x1.x;  xr[5]=x1.y;  xr[6]=x1.z;  xr[7]=x1.w;
    xr[8]=x2.x;  xr[9]=x2.y;  xr[10]=x2.z; xr[11]=x2.w;
    xr[12]=x3.x; xr[13]=x3.y; xr[14]=x3.z; xr[15]=x3.w;

    const bool l0 = (lane == 0);

    // ---- Phase 2 window: w[n] = x[16i - 7 + n], n=0..22 ----
    // Lane 0 override: w[7+m] for m<0 must be x[-m]  (reflect), i.e. w[j]=xr[7-j].
    float w[23];
    {
        float h0 = __shfl_up(xr[9], 1);
        float h1 = __shfl_up(xr[10], 1);
        float h2 = __shfl_up(xr[11], 1);
        float h3 = __shfl_up(xr[12], 1);
        float h4 = __shfl_up(xr[13], 1);
        float h5 = __shfl_up(xr[14], 1);
        float h6 = __shfl_up(xr[15], 1);
        w[0] = l0 ? xr[7] : h0;
        w[1] = l0 ? xr[6] : h1;
        w[2] = l0 ? xr[5] : h2;
        w[3] = l0 ? xr[4] : h3;
        w[4] = l0 ? xr[3] : h4;
        w[5] = l0 ? xr[2] : h5;
        w[6] = l0 ? xr[1] : h6;
    }
#pragma unroll
    for (int n = 0; n < 16; ++n) w[7 + n] = xr[n];

    // ---- Phase 2: (lo,hi)[c], c = 8*lane + q.  lo[c] = sum_j x[2c-j]*dec_lo[j] ----
    float lo[8], hi[8];
#pragma unroll
    for (int q = 0; q < 8; ++q) {
        float aL = 0.f, aH = 0.f;
#pragma unroll
        for (int j = 0; j < 8; ++j) {
            const float v = w[7 + 2 * q - j];
            aL = fmaf(v, f_dlo[j], aL);
            aH = fmaf(v, f_dhi[j], aH);
        }
        lo[q] = aL; hi[q] = aH;
    }

    // ---- Sparse add: 10 uniform (s,v); c<512 -> lo, c>=516 -> hi; [512,516) unused ----
    for (int n = 0; n < NS; ++n) {
        const int   s = sp_i[n];
        const float v = sp_c[n];
        const bool isLo = (s < 512);
        const bool isHi = (s >= 516);
        const int  c    = isLo ? s : (s - 516);
        const int  q    = c & 7;
        const bool mine = (lane == (c >> 3)) && (isLo || isHi);
        const float vL = (mine && isLo) ? v : 0.f;
        const float vH = (mine && isHi) ? v : 0.f;
#pragma unroll
        for (int qq = 0; qq < 8; ++qq) {
            if (q == qq) { lo[qq] += vL; hi[qq] += vH; }   // uniform branch on q
        }
    }

    // ---- Phase 3 pair window: P[n] = (lo,hi) at c = 8*lane - 3 + n, n=0..10 ----
    // Lane 0 override: slot n (c_rel = n-3 < 0) reflects to own pair c = 3-n.
    float Plo[11], Phi[11];
    {
        float a0 = __shfl_up(lo[5], 1);
        float a1 = __shfl_up(lo[6], 1);
        float a2 = __shfl_up(lo[7], 1);
        float b0 = __shfl_up(hi[5], 1);
        float b1 = __shfl_up(hi[6], 1);
        float b2 = __shfl_up(hi[7], 1);
        Plo[0] = l0 ? lo[3] : a0;
        Plo[1] = l0 ? lo[2] : a1;
        Plo[2] = l0 ? lo[1] : a2;
        Phi[0] = l0 ? hi[3] : b0;
        Phi[1] = l0 ? hi[2] : b1;
        Phi[2] = l0 ? hi[1] : b2;
    }
#pragma unroll
    for (int n = 0; n < 8; ++n) { Plo[3 + n] = lo[n]; Phi[3 + n] = hi[n]; }

    // ---- Phase 3: out[t] = x[t] + sum_k P[(r+k-7)/2 + 3] * rec[k], k parity ~ r ----
    float res[16];
#pragma unroll
    for (int r = 0; r < 16; ++r) {
        const int k0 = (r & 1) ? 0 : 1;
        float a = 0.f;
#pragma unroll
        for (int u = 0; u < 4; ++u) {
            const int k = k0 + 2 * u;
            const int n = (r + k - 7) / 2 + 3;   // exact (even numerator)
            a = fmaf(Plo[n], f_rlo[k], a);
            a = fmaf(Phi[n], f_rhi[k], a);
        }
        res[r] = a;
    }

    // ---- Store out = x + rec (4x dwordx4) ----
    floatx4* ov4 = (floatx4*)(out + base);
    floatx4 r0, r1, r2, r3;
    r0.x = res[0]  + xr[0];  r0.y = res[1]  + xr[1];
    r0.z = res[2]  + xr[2];  r0.w = res[3]  + xr[3];
    r1.x = res[4]  + xr[4];  r1.y = res[5]  + xr[5];
    r1.z = res[6]  + xr[6];  r1.w = res[7]  + xr[7];
    r2.x = res[8]  + xr[8];  r2.y = res[9]  + xr[9];
    r2.z = res[10] + xr[10]; r2.w = res[11] + xr[11];
    r3.x = res[12] + xr[12]; r3.y = res[13] + xr[13];
    r3.z = res[14] + xr[14]; r3.w = res[15] + xr[15];
    ov4[0] = r0; ov4[1] = r1; ov4[2] = r2; ov4[3] = r3;
}

extern "C" void kernel_launch(void* const* d_in, const int* in_sizes, int n_in,
                              void* d_out, int out_size, void* d_ws, size_t ws_size,
                              hipStream_t stream) {
    const float* x      = (const float*)d_in[0];
    const float* dec_lo = (const float*)d_in[1];
    const float* dec_hi = (const float*)d_in[2];
    const float* rec_lo = (const float*)d_in[3];
    const float* rec_hi = (const float*)d_in[4];
    const float* sp_c   = (const float*)d_in[5];
    const int*   sp_i   = (const int*)d_in[6];
    float* out = (float*)d_out;

    const int Brows  = in_sizes[0] / D_LEN;      // 32768
    const int blocks = Brows / 4;                // 4 rows (waves) per 256-thread block
    wavecore_kernel<<<blocks, 256, 0, stream>>>(x, dec_lo, dec_hi, rec_lo, rec_hi,
                                                sp_c, sp_i, out);
}

// Round 5
// 53.772 us; speedup vs baseline: 1.1447x; 1.1447x over previous
//
#include <hip/hip_runtime.h>

// B=32768, D=1024, K=8, NS=10
#define D_LEN 1024
#define K_LEN 8
#define PAD   7
#define LC    516
#define NS    10

// One block (256 threads) per row. Coalesced float4 ownership (thread t owns
// x[4t..4t+3], pairs c=2t,2t+1, out[4t..4t+3]).
//   Phase 1: row -> LDS (1x ds_write_b128/thread).
//   Phase 2: (lo,hi) pairs from 2x ds_read_b128 + own regs; sparse folded into
//            registers (10 uniform (s,v): cmp+cndmask+add); 1x ds_write_b128.
//   Phase 3: 2x ds_read_b128 (neighbor pair-quads) + own quad in regs;
//            parity-collapsed 4-tap reconstruction; residual add; store.
// 2 barriers total. No nontemporal hints (x is partially L3-resident).
__global__ __launch_bounds__(256) void wavecore_kernel(
    const float* __restrict__ x,
    const float* __restrict__ dec_lo, const float* __restrict__ dec_hi,
    const float* __restrict__ rec_lo, const float* __restrict__ rec_hi,
    const float* __restrict__ sp_c,   const int* __restrict__ sp_i,
    float* __restrict__ out)
{
    __shared__ __align__(16) float  sx[D_LEN];
    __shared__ __align__(16) float2 st[512];   // (lo,hi) pairs, c = 0..511

    const int tid = threadIdx.x;
    const size_t rowoff = (size_t)blockIdx.x * D_LEN;

    // ---- Phase 1 ----
    const float4 xv = ((const float4*)(x + rowoff))[tid];
    ((float4*)sx)[tid] = xv;

    float f_dlo[K_LEN], f_dhi[K_LEN], f_rlo[K_LEN], f_rhi[K_LEN];
#pragma unroll
    for (int k = 0; k < K_LEN; ++k) {
        f_dlo[k] = dec_lo[k]; f_dhi[k] = dec_hi[k];
        f_rlo[k] = rec_lo[k]; f_rhi[k] = rec_hi[k];
    }
    __syncthreads();

    // ---- Phase 2: lo[c] = sum_j x[refl(2c-j)] * dec_lo[j], c = 2t, 2t+1 ----
    float lo0 = 0.f, hi0 = 0.f, lo1 = 0.f, hi1 = 0.f;
    if (tid >= 2) {
        const float4 wa = ((const float4*)sx)[tid - 2];   // x[4t-8..4t-5]
        const float4 wb = ((const float4*)sx)[tid - 1];   // x[4t-4..4t-1]
        const float w[12] = { wa.x, wa.y, wa.z, wa.w,
                              wb.x, wb.y, wb.z, wb.w,
                              xv.x, xv.y, xv.z, xv.w };   // x[4t-8..4t+3]
#pragma unroll
        for (int j = 0; j < K_LEN; ++j) {
            const float v0 = w[8  - j];
            const float v1 = w[10 - j];
            lo0 = fmaf(v0, f_dlo[j], lo0);
            hi0 = fmaf(v0, f_dhi[j], hi0);
            lo1 = fmaf(v1, f_dlo[j], lo1);
            hi1 = fmaf(v1, f_dhi[j], hi1);
        }
    } else {
        // Boundary c <= 3: reflect -> sx[abs(2c - j)]
#pragma unroll
        for (int q = 0; q < 2; ++q) {
            const int c = 2 * tid + q;
            float aL = 0.f, aH = 0.f;
#pragma unroll
            for (int j = 0; j < K_LEN; ++j) {
                int m = 2 * c - j;
                m = (m < 0) ? -m : m;
                const float v = sx[m];
                aL = fmaf(v, f_dlo[j], aL);
                aH = fmaf(v, f_dhi[j], aH);
            }
            if (q == 0) { lo0 = aL; hi0 = aH; }
            else        { lo1 = aL; hi1 = aH; }
        }
    }

    // ---- Sparse fold (register-level; 10 uniform (s,v); no extra barrier) ----
#pragma unroll
    for (int n = 0; n < NS; ++n) {
        const int   s = sp_i[n];
        const float v = sp_c[n];
        const bool  isHi = (s >= LC);
        const int   c    = isHi ? (s - LC) : s;
        if (s < 512 || isHi) {                        // uniform; skips lo c>=512
            const float add = (tid == (c >> 1)) ? v : 0.f;
            if (c & 1) { if (isHi) hi1 += add; else lo1 += add; }
            else       { if (isHi) hi0 += add; else lo0 += add; }
        }
    }

    {
        float4 pr; pr.x = lo0; pr.y = hi0; pr.z = lo1; pr.w = hi1;
        ((float4*)st)[tid] = pr;                      // st[2t], st[2t+1]
    }
    __syncthreads();

    // ---- Phase 3: rec + residual ----
    float res0, res1, res2, res3;
    if (tid >= 2) {
        const float4 qa = ((const float4*)st)[tid - 2]; // pairs c=2t-4,2t-3
        const float4 qb = ((const float4*)st)[tid - 1]; // pairs c=2t-2,2t-1
        const float p0l = qa.z, p0h = qa.w;
        const float p1l = qb.x, p1h = qb.y;
        const float p2l = qb.z, p2h = qb.w;
        const float p3l = lo0,  p3h = hi0;              // own pair c=2t
        const float p4l = lo1,  p4h = hi1;              // own pair c=2t+1
        res0 = p0l*f_rlo[1] + p0h*f_rhi[1] + p1l*f_rlo[3] + p1h*f_rhi[3]
             + p2l*f_rlo[5] + p2h*f_rhi[5] + p3l*f_rlo[7] + p3h*f_rhi[7];
        res1 = p0l*f_rlo[0] + p0h*f_rhi[0] + p1l*f_rlo[2] + p1h*f_rhi[2]
             + p2l*f_rlo[4] + p2h*f_rhi[4] + p3l*f_rlo[6] + p3h*f_rhi[6];
        res2 = p1l*f_rlo[1] + p1h*f_rhi[1] + p2l*f_rlo[3] + p2h*f_rhi[3]
             + p3l*f_rlo[5] + p3h*f_rhi[5] + p4l*f_rlo[7] + p4h*f_rhi[7];
        res3 = p1l*f_rlo[0] + p1h*f_rhi[0] + p2l*f_rlo[2] + p2h*f_rhi[2]
             + p3l*f_rlo[4] + p3h*f_rhi[4] + p4l*f_rlo[6] + p4h*f_rhi[6];
    } else {
        float acc[4];
#pragma unroll
        for (int j = 0; j < 4; ++j) {
            const int t  = 4 * tid + j;
            const int k0 = ((j & 1) ^ 1);
            float a = 0.f;
#pragma unroll
            for (int i = 0; i < 4; ++i) {
                const int k = k0 + 2 * i;
                int m = t + k - PAD;
                m = (m < 0) ? -m : m;
                const float2 pv = st[m >> 1];
                a = fmaf(pv.x, f_rlo[k], a);
                a = fmaf(pv.y, f_rhi[k], a);
            }
            acc[j] = a;
        }
        res0 = acc[0]; res1 = acc[1]; res2 = acc[2]; res3 = acc[3];
    }

    float4 r;
    r.x = res0 + xv.x;
    r.y = res1 + xv.y;
    r.z = res2 + xv.z;
    r.w = res3 + xv.w;
    ((float4*)(out + rowoff))[tid] = r;
}

extern "C" void kernel_launch(void* const* d_in, const int* in_sizes, int n_in,
                              void* d_out, int out_size, void* d_ws, size_t ws_size,
                              hipStream_t stream) {
    const float* x      = (const float*)d_in[0];
    const float* dec_lo = (const float*)d_in[1];
    const float* dec_hi = (const float*)d_in[2];
    const float* rec_lo = (const float*)d_in[3];
    const float* rec_hi = (const float*)d_in[4];
    const float* sp_c   = (const float*)d_in[5];
    const int*   sp_i   = (const int*)d_in[6];
    float* out = (float*)d_out;

    const int Brows = in_sizes[0] / D_LEN;   // 32768
    wavecore_kernel<<<Brows, 256, 0, stream>>>(x, dec_lo, dec_hi, rec_lo, rec_hi,
                                               sp_c, sp_i, out);
}